// Round 16
// baseline (70.285 us; speedup 1.0000x reference)
//
#include <hip/hip_runtime.h>

// Conv2d 5x5, C=3, O=1, stride 1, pad 2, N=256, H=W=224, +bias.
// R16 = R15 + chunk-XOR LDS bank spread + pad-zeroing (select-free windows).
//   Evidence: R12 (f2/f4 reads) and R13 (all-b128) had IDENTICAL 1.15e7 bank
//   conflicts -> source is the stride-16B READ pattern (lanes c, c+8 share a
//   bank-quad), not the writes. ~19us/CU of conflict stall.
// Fix (both-sides-or-neither, pre-swizzled global source):
//   - physical chunk position p(k) = k ^ ((k>>3)&7) (involution), RST=256 dw.
//     Lanes c,c+8,c+16.. -> distinct bank-quads; <=2-way per 16-lane group = free.
//   - gl_lds16 dest stays LINEAR (lane*16); the permutation is applied to the
//     per-lane GLOBAL source: lane l stages logical chunk k(l)=l^((l>>3)&7),
//     i.e. global chunk k(l)-1 (logical chunk 0 / 57 are x-pads).
//   - pad slots (logical 0,57) get real zeros (lanes 0,62 ds_write) -> lo/hi
//     cndmasks deleted; windows are 3 raw b128 with immediate offsets.
//   - reads: per-thread vaddrs vA/vB/vC at p(c),p(c+1),p(c+2), all (buf,ch,jj)
//     via compile-time offset immediates (max 41984 < 65536).
// Carried from R15: channel-phase pipeline (stage ch c+1 under compute ch c),
// 6 literal phases, acc in regs across phases, XCD swizzle, grid 3584.
// LDS 2x12288 = 24576 B -> 6 blocks/CU resident.

namespace {

constexpr int Hc = 224, Wc = 224, Cc = 3;
constexpr int HW = Hc * Wc;
constexpr int CHW = Cc * HW;
constexpr int BAND = 8;               // output rows per band
constexpr int SROWS = BAND + 4;       // 12 staged rows per (band, channel)
constexpr int RST = 256;              // LDS row stride (dwords) = 64 chunks
constexpr int BUFD = SROWS * RST;     // 3072 dwords = 12288 B per buffer
constexpr int BPB = 2;                // bands per block
constexpr int SPI = Hc / BAND / BPB;  // 14 strips per image
constexpr int BLK = 256;

__device__ __forceinline__ void gl_lds16(const float* g, float* l) {
  __builtin_amdgcn_global_load_lds(
      (const __attribute__((address_space(1))) void*)g,
      (__attribute__((address_space(3))) void*)l, 16, 0, 0);
}

__device__ __forceinline__ constexpr int pchunk(int k) {
  return k ^ ((k >> 3) & 7);          // involution: bank-quad spread
}

__global__ __launch_bounds__(BLK) void conv5x5_r16(
    const float* __restrict__ x, const float* __restrict__ wl,
    const float* __restrict__ bptr, float* __restrict__ out) {
  __shared__ __align__(16) float sm[2 * BUFD];   // 24576 B

  const int tid = threadIdx.x;
  const int lane = tid & 63;
  const int wv = tid >> 6;

  // Bijective XCD swizzle: 3584 = 8 * 448.
  const int cpx = gridDim.x >> 3;
  const int bid = (blockIdx.x & 7) * cpx + (blockIdx.x >> 3);
  const int n = bid / SPI;                 // image
  const int b0 = (bid % SPI) * BPB;        // first band of this strip

  // Weights: wave-uniform, compile-time offsets -> SGPRs.
  float w[Cc][5][5];
#pragma unroll
  for (int c = 0; c < Cc; ++c)
#pragma unroll
    for (int i = 0; i < 25; ++i) w[c][i / 5][i % 5] = wl[c * 25 + i];
  const float bias = bptr[0];

  const float* xn = x + (size_t)n * CHW;
  float* outn = out + (size_t)n * HW;

  // ---- staging roles (per lane, fixed) ----
  // Physical slot `lane` holds logical chunk k(lane) (involution). Logical
  // chunk k in [1,56] holds global chunk k-1; k==0 / k==57 are x-pad slots
  // (zero-filled); k in [58,63] are never read.
  const int klane = lane ^ ((lane >> 3) & 7);
  const bool stg = (klane >= 1) && (klane <= 56);
  const bool padw = (klane == 0) || (klane == 57);
  const int goff = (klane - 1) * 4;        // global dword offset within row

  // ---- compute roles: 224 threads = 56 cols x 4 row-groups; 4x2 outputs ----
  const bool active = tid < 224;
  const int col = tid % 56;
  const int tg = tid / 56;
  // Per-thread read bases (dwords): row tg*2, chunks p(col..col+2). All
  // (buf, ch, jj) deltas are compile-time offset immediates on the ds_read.
  const float* vA = sm + tg * 2 * RST + pchunk(col) * 4;
  const float* vB = sm + tg * 2 * RST + pchunk(col + 1) * 4;
  const float* vC = sm + tg * 2 * RST + pchunk(col + 2) * 4;

  float4 a0, a1;                           // band accumulators (live across
                                           // the 3 channel phases of a band)

  // Stage phase P (literal): 12 rows of channel P%3, band b0+P/3 -> buf P&1.
  // Wave wv owns rows {wv, wv+4, wv+8}. LDS dest = wave-uniform row base
  // (HW adds lane*16). In-bounds rows: lanes stage permuted global chunks,
  // pad lanes write zeros. OOB rows (y pad): all lanes write zeros.
#define STAGE_P(P)                                                            \
  do {                                                                        \
    const int band_ = b0 + (P) / 3;                                           \
    const float* gch_ = xn + (size_t)((P) % 3) * HW;                          \
    float* smb_ = sm + ((P) & 1) * BUFD;                                      \
    _Pragma("unroll") for (int i_ = 0; i_ < 3; ++i_) {                        \
      const int r_ = wv + 4 * i_;                                             \
      const int gy_ = band_ * BAND - 2 + r_;                                  \
      float* ldrow_ = smb_ + r_ * RST;                                        \
      if (gy_ >= 0 && gy_ < Hc) {                                             \
        const float* grow_ = gch_ + (size_t)gy_ * Wc;                         \
        if (stg) gl_lds16(grow_ + goff, ldrow_);                              \
        if (padw)                                                             \
          *(float4*)(ldrow_ + lane * 4) = make_float4(0.f, 0.f, 0.f, 0.f);    \
      } else {                                                                \
        *(float4*)(ldrow_ + lane * 4) = make_float4(0.f, 0.f, 0.f, 0.f);      \
      }                                                                       \
    }                                                                         \
  } while (0)

  // Compute phase P (literal) from buf P&1. Window = 3 raw b128 (no masks:
  // x-pads are real zeros). win[j] = global[4c-2+j] = {A.z,A.w,B.xyzw,C.x,C.y}.
#define COMPUTE_P(P)                                                          \
  do {                                                                        \
    constexpr int ch_ = (P) % 3;                                              \
    constexpr int base_ = ((P) & 1) * BUFD + ch_ * 0;                         \
    const int band_ = b0 + (P) / 3;                                           \
    if (ch_ == 0) {                                                           \
      a0 = make_float4(0.f, 0.f, 0.f, 0.f);                                   \
      a1 = make_float4(0.f, 0.f, 0.f, 0.f);                                   \
    }                                                                         \
    if (active) {                                                             \
      _Pragma("unroll") for (int jj_ = 0; jj_ < 6; ++jj_) {                   \
        constexpr int off0_ = base_;                                          \
        const int off_ = off0_ + jj_ * RST;    /* + ch via below */           \
        const float4 A_ = *(const float4*)(vA + off_);                        \
        const float4 B_ = *(const float4*)(vB + off_);                        \
        const float4 C_ = *(const float4*)(vC + off_);                        \
        float win_[8];                                                        \
        win_[0] = A_.z; win_[1] = A_.w;                                       \
        win_[2] = B_.x; win_[3] = B_.y; win_[4] = B_.z; win_[5] = B_.w;       \
        win_[6] = C_.x; win_[7] = C_.y;                                       \
        if (jj_ <= 4) {                                                       \
          _Pragma("unroll") for (int kx_ = 0; kx_ < 5; ++kx_) {               \
            const float wv_ = w[ch_][jj_][kx_];                               \
            a0.x = fmaf(win_[kx_ + 0], wv_, a0.x);                            \
            a0.y = fmaf(win_[kx_ + 1], wv_, a0.y);                            \
            a0.z = fmaf(win_[kx_ + 2], wv_, a0.z);                            \
            a0.w = fmaf(win_[kx_ + 3], wv_, a0.w);                            \
          }                                                                   \
        }                                                                     \
        if (jj_ >= 1) {                                                       \
          _Pragma("unroll") for (int kx_ = 0; kx_ < 5; ++kx_) {               \
            const float wv_ = w[ch_][jj_ - 1][kx_];                           \
            a1.x = fmaf(win_[kx_ + 0], wv_, a1.x);                            \
            a1.y = fmaf(win_[kx_ + 1], wv_, a1.y);                            \
            a1.z = fmaf(win_[kx_ + 2], wv_, a1.z);                            \
            a1.w = fmaf(win_[kx_ + 3], wv_, a1.w);                            \
          }                                                                   \
        }                                                                     \
      }                                                                       \
      if (ch_ == 2) {                                                         \
        const int gy0_ = band_ * BAND + tg * 2;                               \
        float* op_ = outn + (size_t)gy0_ * Wc + col * 4;                      \
        float4 o0, o1;                                                        \
        o0.x = a0.x + bias; o0.y = a0.y + bias;                               \
        o0.z = a0.z + bias; o0.w = a0.w + bias;                               \
        o1.x = a1.x + bias; o1.y = a1.y + bias;                               \
        o1.z = a1.z + bias; o1.w = a1.w + bias;                               \
        *(float4*)op_ = o0;                                                   \
        *(float4*)(op_ + Wc) = o1;                                            \
      }                                                                       \
    }                                                                         \
  } while (0)

  // NOTE: buffer/channel offsets fold into the single runtime index `off_`:
  // the channel lives in the STAGED buffer, not the address (one channel per
  // buffer), so off_ needs only (buf, jj) -- both compile-time per phase.

  // ---- pipeline, phases expanded with literal constants ----
  STAGE_P(0);
  __syncthreads(); STAGE_P(1); COMPUTE_P(0);
  __syncthreads(); STAGE_P(2); COMPUTE_P(1);
  __syncthreads(); STAGE_P(3); COMPUTE_P(2);
  __syncthreads(); STAGE_P(4); COMPUTE_P(3);
  __syncthreads(); STAGE_P(5); COMPUTE_P(4);
  __syncthreads();             COMPUTE_P(5);

#undef STAGE_P
#undef COMPUTE_P
}

}  // namespace

extern "C" void kernel_launch(void* const* d_in, const int* in_sizes, int n_in,
                              void* d_out, int out_size, void* d_ws, size_t ws_size,
                              hipStream_t stream) {
  const float* x  = (const float*)d_in[0];   // [N,3,224,224] f32
  const float* wl = (const float*)d_in[1];   // [1,75] f32
  const float* b  = (const float*)d_in[2];   // [1] f32
  float* out = (float*)d_out;                // [N,224,224] f32

  const int N = out_size / HW;               // 256
  const int nblk = N * SPI;                  // 3584 = 8 * 448

  conv5x5_r16<<<nblk, BLK, 0, stream>>>(x, wl, b, out);
}

// Round 17
// 45.049 us; speedup vs baseline: 1.5602x; 1.5602x over previous
//
#include <hip/hip_runtime.h>

// Conv2d 5x5, C=3, O=1, stride 1, pad 2, N=256, H=W=224, +bias.
// R17 = R15 with BAND=16/BPB=1 (y-halo amortization), LDS geometry untouched.
//   R16 post-mortem: XOR chunk swizzle CANNOT reduce b128 read conflicts
//   (16-lane groups already cover bank-quads 2x with linear chunks; a
//   permutation preserves mod-8 coverage) and RST 232->256 + pad-writes
//   regressed 53.4->70.3. Reverted all of it.
//   R15 remains best (53.4us): channel-phase pipeline, RST=232, +4-shift rows.
// This round's single change: BAND 8->16 (BPB 2->1), same outputs/block:
//   - stage 60 rows/block vs 72 (-17% stage traffic)
//   - 24 b128 read-triplets/thread vs 36 (-33% ds_reads)
//   - 3 barriers/block vs 6
//   - cost: dbuf 2x18560=37120 B -> 4 blocks/CU (vs 7); compute phase is 2x
//     longer so stage(p+1) hides under 2x the FMA work.
// Thread = 4 cols x 4 rows (tg*4); acc = 4 float4, all statically indexed.

namespace {

constexpr int Hc = 224, Wc = 224, Cc = 3;
constexpr int HW = Hc * Wc;
constexpr int CHW = Cc * HW;
constexpr int BAND = 16;              // output rows per band (= per block)
constexpr int SROWS = BAND + 4;       // 20 staged rows per (band, channel)
constexpr int RST = 232;              // LDS row stride (dwords); 232%32 = 8
constexpr int BUFD = SROWS * RST;     // 4640 dwords = 18560 B per buffer
constexpr int SPI = Hc / BAND;        // 14 bands (strips) per image
constexpr int BLK = 256;

__device__ __forceinline__ void gl_lds16(const float* g, float* l) {
  __builtin_amdgcn_global_load_lds(
      (const __attribute__((address_space(1))) void*)g,
      (__attribute__((address_space(3))) void*)l, 16, 0, 0);
}

__global__ __launch_bounds__(BLK) void conv5x5_r17(
    const float* __restrict__ x, const float* __restrict__ wl,
    const float* __restrict__ bptr, float* __restrict__ out) {
  __shared__ __align__(16) float sm[2 * BUFD];   // 37120 B

  const int tid = threadIdx.x;
  const int lane = tid & 63;
  const int wv = tid >> 6;

  // Bijective XCD swizzle: 3584 = 8 * 448.
  const int cpx = gridDim.x >> 3;
  const int bid = (blockIdx.x & 7) * cpx + (blockIdx.x >> 3);
  const int n = bid / SPI;                 // image
  const int band = bid % SPI;              // band index (16 rows)

  // Weights: wave-uniform, compile-time offsets -> SGPRs.
  float w[Cc][5][5];
#pragma unroll
  for (int c = 0; c < Cc; ++c)
#pragma unroll
    for (int i = 0; i < 25; ++i) w[c][i / 5][i % 5] = wl[c * 25 + i];
  const float bias = bptr[0];

  const float* xn = x + (size_t)n * CHW;
  float* outn = out + (size_t)n * HW;

  // Compute roles: 224 threads = 56 cols x 4 row-groups; thread = 4x4 outputs.
  const bool active = tid < 224;
  const int col = tid % 56;
  const int tg = tid / 56;
  const bool lo = (col == 0), hi = (col == 55);
  const int rdo = col * 4;                 // read base (dwords) within a row

  float4 acc[4];                           // 4 output rows, live across phases

  // Stage phase P (literal): 20 rows of channel P, band `band`, into buffer
  // P&1. Wave wv owns rows {wv, wv+4, wv+8, wv+12, wv+16}. LDS dest is the
  // wave-uniform row base (+4-dword shift); HW adds lane*16 (lanes >= 56
  // masked; row data = dwords 4..227, global dword j at LDS dword j+4).
  // OOB rows (y pad: band 0 r<2, band 13 r>=18) zero-filled.
#define STAGE_P(P)                                                            \
  do {                                                                        \
    const float* gch_ = xn + (size_t)(P) * HW;                                \
    float* smb_ = sm + ((P) & 1) * BUFD;                                      \
    _Pragma("unroll") for (int i_ = 0; i_ < 5; ++i_) {                        \
      const int r_ = wv + 4 * i_;                                             \
      const int gy_ = band * BAND - 2 + r_;                                   \
      float* ld_ = smb_ + r_ * RST + 4;                                       \
      if (gy_ >= 0 && gy_ < Hc) {                                             \
        if (lane < 56)                                                        \
          gl_lds16(gch_ + (size_t)gy_ * Wc + lane * 4, ld_);                  \
      } else {                                                                \
        if (lane < 56)                                                        \
          *(float4*)(ld_ + lane * 4) = make_float4(0.f, 0.f, 0.f, 0.f);       \
      }                                                                       \
    }                                                                         \
  } while (0)

  // Compute phase P (literal) from buffer P&1. Thread reads LDS rows
  // tg*4 + jj, jj=0..7; output row r (0..3) taps jj = r..r+4 (ky = jj-r).
  // Window = 3 aligned b128: A @ dword 4c, B @ 4c+4, C @ 4c+8;
  // win[j] = global[4c-2+j] = {A.z,A.w,B.xyzw,C.x,C.y}; lo/hi masked.
#define COMPUTE_P(P)                                                          \
  do {                                                                        \
    constexpr int ch_ = (P);                                                  \
    const float* smb_ = sm + ((P) & 1) * BUFD;                                \
    if (ch_ == 0) {                                                           \
      _Pragma("unroll") for (int r_ = 0; r_ < 4; ++r_)                        \
          acc[r_] = make_float4(0.f, 0.f, 0.f, 0.f);                          \
    }                                                                         \
    if (active) {                                                             \
      _Pragma("unroll") for (int jj_ = 0; jj_ < 8; ++jj_) {                   \
        const float* rp_ = smb_ + (tg * 4 + jj_) * RST + rdo;                 \
        const float4 A_ = *(const float4*)rp_;                                \
        const float4 B_ = *(const float4*)(rp_ + 4);                          \
        const float4 C_ = *(const float4*)(rp_ + 8);                          \
        float win_[8];                                                        \
        win_[0] = lo ? 0.f : A_.z;                                            \
        win_[1] = lo ? 0.f : A_.w;                                            \
        win_[2] = B_.x; win_[3] = B_.y; win_[4] = B_.z; win_[5] = B_.w;       \
        win_[6] = hi ? 0.f : C_.x;                                            \
        win_[7] = hi ? 0.f : C_.y;                                            \
        _Pragma("unroll") for (int r_ = 0; r_ < 4; ++r_) {                    \
          if (r_ <= jj_ && jj_ - r_ <= 4) {                                   \
            _Pragma("unroll") for (int kx_ = 0; kx_ < 5; ++kx_) {             \
              const float wv_ = w[ch_][jj_ - r_][kx_];                        \
              acc[r_].x = fmaf(win_[kx_ + 0], wv_, acc[r_].x);                \
              acc[r_].y = fmaf(win_[kx_ + 1], wv_, acc[r_].y);                \
              acc[r_].z = fmaf(win_[kx_ + 2], wv_, acc[r_].z);                \
              acc[r_].w = fmaf(win_[kx_ + 3], wv_, acc[r_].w);                \
            }                                                                 \
          }                                                                   \
        }                                                                     \
      }                                                                       \
      if (ch_ == 2) {                                                         \
        const int gy0_ = band * BAND + tg * 4;                                \
        float* op_ = outn + (size_t)gy0_ * Wc + col * 4;                      \
        _Pragma("unroll") for (int r_ = 0; r_ < 4; ++r_) {                    \
          float4 oo_;                                                         \
          oo_.x = acc[r_].x + bias; oo_.y = acc[r_].y + bias;                 \
          oo_.z = acc[r_].z + bias; oo_.w = acc[r_].w + bias;                 \
          *(float4*)(op_ + (size_t)r_ * Wc) = oo_;                            \
        }                                                                     \
      }                                                                       \
    }                                                                         \
  } while (0)

  // ---- pipeline: stage(P+1) flies under compute(P); 3 barriers total ----
  STAGE_P(0);
  __syncthreads(); STAGE_P(1); COMPUTE_P(0);
  __syncthreads(); STAGE_P(2); COMPUTE_P(1);
  __syncthreads();             COMPUTE_P(2);

#undef STAGE_P
#undef COMPUTE_P
}

}  // namespace

extern "C" void kernel_launch(void* const* d_in, const int* in_sizes, int n_in,
                              void* d_out, int out_size, void* d_ws, size_t ws_size,
                              hipStream_t stream) {
  const float* x  = (const float*)d_in[0];   // [N,3,224,224] f32
  const float* wl = (const float*)d_in[1];   // [1,75] f32
  const float* b  = (const float*)d_in[2];   // [1] f32
  float* out = (float*)d_out;                // [N,224,224] f32

  const int N = out_size / HW;               // 256
  const int nblk = N * SPI;                  // 3584 = 8 * 448

  conv5x5_r17<<<nblk, BLK, 0, stream>>>(x, wl, b, out);
}